// Round 10
// baseline (89.084 us; speedup 1.0000x reference)
//
#include <hip/hip_runtime.h>
#include <utility>

#define IMG_H 512
#define IMG_W 512

typedef _Float16 h2 __attribute__((ext_vector_type(2)));

__device__ __forceinline__ h2 h2min(h2 a, h2 b) { return __builtin_elementwise_min(a, b); }
__device__ __forceinline__ h2 h2max(h2 a, h2 b) { return __builtin_elementwise_max(a, b); }

// ---------------------------------------------------------------------------
// Compile-time linear program, round 10: MOV-FREE construction.
//  - runs are compile-time slot LISTS; merges mutate sources in place
//  - pad-vs-real CEs become slot-map renames (zero instructions)
//  - rank-select uses 3-address v_pk_max (kind 7), no staging movs
//  - copies only where a run is read twice (g2,g4,g6, M56, M78, C28A, C28B)
//  - then r8's backward prune (+min/max degradation) and linear-scan regalloc
// kinds: 0 ce(a,b)  1 mov a<-b  2 load a<-cols[b]  3 store med[a]<-v[b]
//        4 a=min(a,b)  5 b=max(a,b)  7 c=max(a,b)
// ---------------------------------------------------------------------------
struct Op { int kind, a, b, c; };
constexpr int NSLOT = 512;    // virtual slot space (bump-allocated)
constexpr int MAXOPS = 4096;
struct Prog { Op ops[MAXOPS]; int n; int nphys; bool ok; };

constexpr int pow2ceil(int x) { int p = 1; while (p < x) p += p; return p; }

struct Run { int s[48]; int len; };

struct Builder {
    Op ops[MAXOPS] = {};
    int n = 0;
    int nv = 0;
    bool ok = true;

    constexpr void emit(int k, int a, int b, int c) {
        if (n < MAXOPS) ops[n++] = Op{k, a, b, c}; else ok = false;
    }
    constexpr int fresh() {
        if (nv < NSLOT) return nv++;
        ok = false; return 0;
    }
    // load packed column c (7 elems) and sort it (validated Batcher-7)
    constexpr Run load_col(int c) {
        Run r{}; r.len = 7;
        for (int i = 0; i < 7; ++i) { r.s[i] = fresh(); emit(2, r.s[i], c * 7 + i, 0); }
        for (int p = 1; p < 7; p += p)
            for (int k = p; k > 0; k /= 2)
                for (int j = k % p; j + k < 7; j += k + k)
                    for (int i = 0; i < k; ++i)
                        if (i + j + k < 7 && (i + j) / (p + p) == (i + j + k) / (p + p))
                            emit(0, r.s[i + j], r.s[i + j + k], 0);
        return r;
    }
    constexpr Run copy(const Run& a) {
        Run r{}; r.len = a.len;
        for (int i = 0; i < a.len; ++i) { r.s[i] = fresh(); emit(1, r.s[i], a.s[i], 0); }
        return r;
    }
    // destructive merge of two sorted runs (Batcher odd-even merge, validated
    // topology; pads are +inf tracked as map=-1, pad-vs-real = pure rename)
    constexpr Run merge(const Run& A, const Run& B) {
        int P = pow2ceil(A.len > B.len ? A.len : B.len);
        if (A.len > P || B.len > P || 2 * P > 96) { ok = false; }
        int map[96] = {};
        for (int i = 0; i < 2 * P; ++i) map[i] = -1;
        for (int i = 0; i < A.len; ++i) map[i] = A.s[i];
        for (int i = 0; i < B.len; ++i) map[P + i] = B.s[i];
        for (int k = P; k > 0; k /= 2)
            for (int j = k % P; j + k < 2 * P; j += k + k)
                for (int i = 0; i < k; ++i) {
                    int x = i + j, y = i + j + k;
                    int a = map[x], b = map[y];
                    if (a >= 0 && b >= 0) emit(0, a, b, 0);
                    else if (a < 0 && b >= 0) { map[x] = b; map[y] = -1; }
                }
        Run r{}; r.len = A.len + B.len;
        for (int i = 0; i < r.len; ++i) { if (map[i] < 0) ok = false; r.s[i] = map[i]; }
        for (int i = r.len; i < 2 * P; ++i) if (map[i] >= 0) ok = false;
        return r;
    }
    // rank-24 of sorted-42 A ∪ sorted-7 B (validated min-of-max identity),
    // nondestructive on A and B.
    constexpr void select49(const Run& A, const Run& B, int o) {
        if (A.len != 42 || B.len != 7) ok = false;
        int T[7] = {};
        for (int t = 0; t < 7; ++t) {
            T[t] = fresh();
            emit(7, A.s[17 + t], B.s[6 - t], T[t]);   // T = max(A[17+t], B[6-t])
        }
        emit(4, T[0], T[1], 0); emit(4, T[2], T[3], 0);
        emit(4, T[4], T[5], 0); emit(4, T[6], A.s[24], 0);  // i=25 candidate
        emit(4, T[0], T[2], 0); emit(4, T[4], T[6], 0);
        emit(4, T[0], T[4], 0);
        emit(3, o, T[0], 0);
    }
};

constexpr Prog build() {
    Builder b{};
    // liveness-minimizing order; selects precede the merges that consume
    // their column where possible (g7, g9, g11 need no copies).
    Run g1 = b.load_col(1), g2 = b.load_col(2), g3 = b.load_col(3),
        g4 = b.load_col(4), g5 = b.load_col(5), g6 = b.load_col(6),
        g7 = b.load_col(7), g8 = b.load_col(8);
    Run g2c = b.copy(g2), g4c = b.copy(g4), g6c = b.copy(g6);

    Run M12 = b.merge(g1, g2c);
    Run M34 = b.merge(g3, g4c);
    Run M56 = b.merge(g5, g6c);
    Run M56b = b.copy(M56);
    Run C28A = b.merge(M34, M56);
    Run C28Ac = b.copy(C28A);
    Run C42A = b.merge(C28Ac, M12);        // sorted42(g1..g6)
    Run g0 = b.load_col(0);
    b.select49(C42A, g0, 0);               // out0: g0..g6
    b.select49(C42A, g7, 1);               // out1: g1..g7

    Run M78 = b.merge(g7, g8);             // g7 consumed after select1
    Run M78b = b.copy(M78);
    Run C42B = b.merge(C28A, M78);         // sorted42(g3..g8)
    Run g9 = b.load_col(9);
    b.select49(C42B, g2, 2);               // out2: g2..g8
    b.select49(C42B, g9, 3);               // out3: g3..g9

    Run g10 = b.load_col(10);
    Run M910 = b.merge(g9, g10);           // g9 consumed after select3
    Run C28B = b.merge(M78b, M910);        // sorted(g7..g10)
    Run C28Bc = b.copy(C28B);
    Run C42C = b.merge(C28Bc, M56b);       // sorted42(g5..g10)
    Run g11 = b.load_col(11);
    b.select49(C42C, g4, 4);               // out4: g4..g10
    b.select49(C42C, g11, 5);              // out5: g5..g11

    Run g12 = b.load_col(12);
    Run M1112 = b.merge(g11, g12);         // g11 consumed after select5
    Run C42D = b.merge(C28B, M1112);       // sorted42(g7..g12)
    Run g13 = b.load_col(13);
    b.select49(C42D, g6, 6);               // out6: g6..g12
    b.select49(C42D, g13, 7);              // out7: g7..g13

    // ---- backward prune + min/max degradation (r8 machinery + kind 7) ----
    Prog p{};
    bool needed[NSLOT] = {};
    int kindr[MAXOPS] = {};
    bool keep[MAXOPS] = {};
    for (int t = b.n - 1; t >= 0; --t) {
        Op o = b.ops[t];
        if (o.kind == 3) { keep[t] = true; kindr[t] = 3; needed[o.b] = true; }
        else if (o.kind == 0) {
            bool na = needed[o.a], nb = needed[o.b];
            if (na && nb)      { keep[t] = true; kindr[t] = 0; }
            else if (na)       { keep[t] = true; kindr[t] = 4; needed[o.b] = true; }
            else if (nb)       { keep[t] = true; kindr[t] = 5; needed[o.a] = true; }
        } else if (o.kind == 1) {
            if (needed[o.a]) { keep[t] = true; kindr[t] = 1; needed[o.a] = false; needed[o.b] = true; }
        } else if (o.kind == 2) {
            if (needed[o.a]) { keep[t] = true; kindr[t] = 2; needed[o.a] = false; }
        } else if (o.kind == 4) {
            if (needed[o.a]) { keep[t] = true; kindr[t] = 4; needed[o.b] = true; }
        } else if (o.kind == 5) {
            if (needed[o.b]) { keep[t] = true; kindr[t] = 5; needed[o.a] = true; }
        } else if (o.kind == 7) {
            if (needed[o.c]) { keep[t] = true; kindr[t] = 7; needed[o.c] = false;
                               needed[o.a] = true; needed[o.b] = true; }
        }
    }
    p.n = 0;
    for (int t = 0; t < b.n; ++t)
        if (keep[t]) { p.ops[p.n] = b.ops[t]; p.ops[p.n].kind = kindr[t]; ++p.n; }
    p.ok = b.ok;

    // ---- liveness / last-use flags ----
    bool live[NSLOT] = {};
    bool lu_a[MAXOPS] = {};
    bool lu_b[MAXOPS] = {};
    for (int t = p.n - 1; t >= 0; --t) {
        Op o = p.ops[t];
        if (o.kind == 0 || o.kind == 4 || o.kind == 5 || o.kind == 7) {
            lu_a[t] = !live[o.a]; lu_b[t] = !live[o.b];
        } else if (o.kind == 1 || o.kind == 3) {
            lu_b[t] = !live[o.b];
        }
        // kill defs
        if (o.kind == 0) { live[o.a] = false; live[o.b] = false; }
        else if (o.kind == 1 || o.kind == 2 || o.kind == 4) live[o.a] = false;
        else if (o.kind == 5) live[o.b] = false;
        else if (o.kind == 7) live[o.c] = false;
        // gen uses
        if (o.kind == 0 || o.kind == 4 || o.kind == 5 || o.kind == 7) {
            live[o.a] = true; live[o.b] = true;
        } else if (o.kind == 1 || o.kind == 3) live[o.b] = true;
    }
    for (int t = 0; t < p.n; ++t) {
        Op o = p.ops[t];
        if (o.kind == 0 && (lu_a[t] || lu_b[t])) p.ok = false;
        if (o.kind == 4 && lu_a[t]) p.ok = false;
        if (o.kind == 5 && lu_b[t]) p.ok = false;
    }
    // ---- linear-scan regalloc: virtual -> dense physical ----
    int phys[NSLOT] = {};
    bool bound[NSLOT] = {};
    int freelist[NSLOT] = {};
    int nfree = 0, nphys = 0;
    for (int t = 0; t < p.n; ++t) {
        Op o = p.ops[t];
        if (o.kind == 0) {
            if (!bound[o.a] || !bound[o.b]) p.ok = false;
            p.ops[t].a = phys[o.a]; p.ops[t].b = phys[o.b];
        } else if (o.kind == 4) {
            if (!bound[o.a] || !bound[o.b]) p.ok = false;
            p.ops[t].a = phys[o.a]; p.ops[t].b = phys[o.b];
            if (lu_b[t]) { freelist[nfree++] = phys[o.b]; bound[o.b] = false; }
        } else if (o.kind == 5) {
            if (!bound[o.a] || !bound[o.b]) p.ok = false;
            p.ops[t].a = phys[o.a]; p.ops[t].b = phys[o.b];
            if (lu_a[t]) { freelist[nfree++] = phys[o.a]; bound[o.a] = false; }
        } else if (o.kind == 7) {
            if (!bound[o.a] || !bound[o.b]) p.ok = false;
            p.ops[t].a = phys[o.a]; p.ops[t].b = phys[o.b];
            if (lu_a[t]) { freelist[nfree++] = phys[o.a]; bound[o.a] = false; }
            if (lu_b[t]) { freelist[nfree++] = phys[o.b]; bound[o.b] = false; }
            int pc = (nfree > 0) ? freelist[--nfree] : nphys++;
            phys[o.c] = pc; bound[o.c] = true;
            p.ops[t].c = pc;
        } else if (o.kind == 1) {
            if (!bound[o.b]) p.ok = false;
            int pb = phys[o.b];
            p.ops[t].b = pb;
            if (lu_b[t]) { freelist[nfree++] = pb; bound[o.b] = false; }
            int pa = (nfree > 0) ? freelist[--nfree] : nphys++;
            phys[o.a] = pa; bound[o.a] = true;
            p.ops[t].a = pa;
        } else if (o.kind == 2) {
            int pa = (nfree > 0) ? freelist[--nfree] : nphys++;
            phys[o.a] = pa; bound[o.a] = true;
            p.ops[t].a = pa;
        } else {  // store
            if (!bound[o.b]) p.ok = false;
            p.ops[t].b = phys[o.b];
            if (lu_b[t]) { freelist[nfree++] = phys[o.b]; bound[o.b] = false; }
        }
        if (nphys > NSLOT || nfree > NSLOT) p.ok = false;
    }
    p.nphys = nphys;
    return p;
}

constexpr Prog PROG = build();
static_assert(PROG.ok, "program build failed");
static_assert(PROG.n > 300 && PROG.n < 2400, "op count out of range");
static_assert(PROG.nphys > 0 && PROG.nphys <= 256, "regalloc blew up");

// ---- banked physical frame: every alloca <= 64 elements ----
template <int P>
__device__ __forceinline__ h2& vslot(h2* v0, h2* v1, h2* v2, h2* v3) {
    if constexpr (P < 64) return v0[P];
    else if constexpr (P < 128) return v1[P - 64];
    else if constexpr (P < 192) return v2[P - 128];
    else return v3[P - 192];
}
template <int P>
__device__ __forceinline__ h2 cslot(const h2* c0, const h2* c1) {
    if constexpr (P < 49) return c0[P];
    else return c1[P - 49];
}

template <int I>
__device__ __forceinline__ void step(h2* v0, h2* v1, h2* v2, h2* v3,
                                     const h2* c0, const h2* c1, h2* med) {
    constexpr Op o = PROG.ops[I];
    if constexpr (o.kind == 0) {
        h2& A = vslot<o.a>(v0, v1, v2, v3);
        h2& B = vslot<o.b>(v0, v1, v2, v3);
        h2 lo = h2min(A, B);
        h2 hi = h2max(A, B);
        A = lo; B = hi;
    } else if constexpr (o.kind == 1) {
        vslot<o.a>(v0, v1, v2, v3) = vslot<o.b>(v0, v1, v2, v3);
    } else if constexpr (o.kind == 2) {
        vslot<o.a>(v0, v1, v2, v3) = cslot<o.b>(c0, c1);
    } else if constexpr (o.kind == 3) {
        med[o.a] = vslot<o.b>(v0, v1, v2, v3);
    } else if constexpr (o.kind == 4) {
        h2& A = vslot<o.a>(v0, v1, v2, v3);
        A = h2min(A, vslot<o.b>(v0, v1, v2, v3));
    } else if constexpr (o.kind == 5) {
        h2& B = vslot<o.b>(v0, v1, v2, v3);
        B = h2max(vslot<o.a>(v0, v1, v2, v3), B);
    } else {  // kind 7: 3-address max
        vslot<o.c>(v0, v1, v2, v3) =
            h2max(vslot<o.a>(v0, v1, v2, v3), vslot<o.b>(v0, v1, v2, v3));
    }
}

template <size_t... Is>
__device__ __forceinline__ void run_all(h2* v0, h2* v1, h2* v2, h2* v3,
                                        const h2* c0, const h2* c1, h2* med,
                                        std::index_sequence<Is...>) {
    (step<(int)Is>(v0, v1, v2, v3, c0, c1, med), ...);
}

// Each thread: 8 (horizontal) x 2 (vertical, packed f16 halves) output pixels.
__global__ __launch_bounds__(256, 2) void median7x7_kernel(
        const float* __restrict__ img, float* __restrict__ out) {
    const int bc = blockIdx.z;
    const int tx = threadIdx.x;                    // 0..63
    const int ty = threadIdx.y;                    // 0..3
    const int x0 = (blockIdx.x * 64 + tx) * 8;     // 0..504
    const int y  = (blockIdx.y * 4 + ty) * 2;      // 0..510

    const float* base = img + (size_t)bc * (IMG_H * IMG_W);
    const bool okl = (x0 >= 4);          // false only for tx == 0
    const bool okr = (x0 <= 496);        // false only for tx == 63
    const int xl = okl ? (x0 - 4) : 0;
    const int xr = okr ? (x0 + 8) : 504;

    // Packed columns, two <=49-element banks:
    // logical colv[c*7+d] = (img[y-3+d][gc], img[y-2+d][gc]), gc = x0-3+c.
    h2 c0[49], c1[49];
    float prv[14];
#pragma unroll
    for (int r = 0; r < 8; ++r) {
        const int yy = y - 3 + r;
        float4 Q0, Q1, Q2, Q3;
        if ((unsigned)yy < IMG_H) {   // wave-uniform (blockDim.x == 64)
            const float* rp = base + (size_t)yy * IMG_W;
            Q0 = *(const float4*)(rp + xl);
            Q1 = *(const float4*)(rp + x0);
            Q2 = *(const float4*)(rp + x0 + 4);
            Q3 = *(const float4*)(rp + xr);
        } else {
            Q0 = make_float4(0.f, 0.f, 0.f, 0.f); Q1 = Q0; Q2 = Q0; Q3 = Q0;
        }
        float cur[14];
        cur[0] = okl ? Q0.y : 0.f; cur[1] = okl ? Q0.z : 0.f; cur[2] = okl ? Q0.w : 0.f;
        cur[3] = Q1.x; cur[4] = Q1.y; cur[5] = Q1.z; cur[6] = Q1.w;
        cur[7] = Q2.x; cur[8] = Q2.y; cur[9] = Q2.z; cur[10] = Q2.w;
        cur[11] = okr ? Q3.x : 0.f; cur[12] = okr ? Q3.y : 0.f; cur[13] = okr ? Q3.z : 0.f;
        if (r > 0) {
#pragma unroll
            for (int c = 0; c < 14; ++c) {
                const int idx = c * 7 + (r - 1);   // constant after unroll
                h2 val = (h2)__builtin_amdgcn_cvt_pkrtz(prv[c], cur[c]);
                if (idx < 49) c0[idx] = val; else c1[idx - 49] = val;
            }
        }
#pragma unroll
        for (int c = 0; c < 14; ++c) prv[c] = cur[c];
    }

    h2 va[64], vb[64], vc[64], vd[64];
    h2 med[8];
    run_all(va, vb, vc, vd, c0, c1, med, std::make_index_sequence<(size_t)PROG.n>{});

    float* op = out + (size_t)bc * (IMG_H * IMG_W) + (size_t)y * IMG_W + x0;
    *(float4*)op = make_float4((float)med[0].x, (float)med[1].x,
                               (float)med[2].x, (float)med[3].x);
    *(float4*)(op + 4) = make_float4((float)med[4].x, (float)med[5].x,
                                     (float)med[6].x, (float)med[7].x);
    *(float4*)(op + IMG_W) = make_float4((float)med[0].y, (float)med[1].y,
                                         (float)med[2].y, (float)med[3].y);
    *(float4*)(op + IMG_W + 4) = make_float4((float)med[4].y, (float)med[5].y,
                                             (float)med[6].y, (float)med[7].y);
}

extern "C" void kernel_launch(void* const* d_in, const int* in_sizes, int n_in,
                              void* d_out, int out_size, void* d_ws, size_t ws_size,
                              hipStream_t stream) {
    const float* img = (const float*)d_in[0];
    float* out = (float*)d_out;
    dim3 grid(1, 64, 24);
    dim3 block(64, 4, 1);
    hipLaunchKernelGGL(median7x7_kernel, grid, block, 0, stream, img, out);
}